// Round 1
// baseline (180.442 us; speedup 1.0000x reference)
//
#include <hip/hip_runtime.h>
#include <hip/hip_bf16.h>
#include <stdint.h>

#define N_NODES 8192
#define N_EDGES 262144
#define IN_F 512
#define HID 512
#define OUT_F 256
#define CAP 128   // max distinct out-neighbors per node; Poisson(32) => P(>128) ~ 0

typedef __attribute__((ext_vector_type(8))) short short8;
typedef __attribute__((ext_vector_type(4))) float f32x4;

// ---------- bf16 helpers (RNE) ----------
__device__ __forceinline__ float bflo(unsigned int u) {
  union { unsigned int x; float f; } c; c.x = u << 16; return c.f;
}
__device__ __forceinline__ float bfhi(unsigned int u) {
  union { unsigned int x; float f; } c; c.x = u & 0xffff0000u; return c.f;
}
__device__ __forceinline__ unsigned short f2bf(float f) {
  union { float f; unsigned int u; } c; c.f = f;
  unsigned int r = c.u + 0x7fffu + ((c.u >> 16) & 1u);
  return (unsigned short)(r >> 16);
}

__device__ __forceinline__ void gload_lds16(const void* g, void* l) {
  __builtin_amdgcn_global_load_lds((const __attribute__((address_space(1))) void*)g,
                                   (__attribute__((address_space(3))) void*)l, 16, 0, 0);
}

// ---------- graph build ----------
__global__ void build_adj(const int* __restrict__ ei, unsigned int* __restrict__ bitmap,
                          int* __restrict__ cnt, int* __restrict__ adj) {
  int e = blockIdx.x * blockDim.x + threadIdx.x;
  if (e >= N_EDGES) return;
  int i = ei[e];
  int j = ei[N_EDGES + e];
  int lin = i * N_NODES + j;
  unsigned int bit = 1u << (lin & 31);
  unsigned int old = atomicOr(&bitmap[lin >> 5], bit);
  if (!(old & bit)) {
    int p = atomicAdd(&cnt[i], 1);
    if (p < CAP) adj[i * CAP + p] = j;
  }
}

__global__ void calc_dis(const int* __restrict__ cnt, float* __restrict__ dis) {
  int i = blockIdx.x * blockDim.x + threadIdx.x;
  if (i < N_NODES) dis[i] = rsqrtf((float)(cnt[i] + 1));  // degree = distinct nbrs + self-loop
}

// ---------- dtype converts ----------
__global__ void cvt_bf16_vec(const float* __restrict__ in, unsigned short* __restrict__ out, int n4) {
  int idx = blockIdx.x * blockDim.x + threadIdx.x;
  if (idx >= n4) return;
  const float4 v = ((const float4*)in)[idx];
  uint2 o;
  o.x = (unsigned int)f2bf(v.x) | ((unsigned int)f2bf(v.y) << 16);
  o.y = (unsigned int)f2bf(v.z) | ((unsigned int)f2bf(v.w) << 16);
  ((uint2*)out)[idx] = o;
}

__global__ void transpose_bf16(const float* __restrict__ W, unsigned short* __restrict__ Wt,
                               int K, int N) {
  int idx = blockIdx.x * blockDim.x + threadIdx.x;
  if (idx >= K * N) return;
  int k = idx / N, n = idx - k * N;
  Wt[n * K + k] = f2bf(W[idx]);
}

// ---------- bf16 MFMA GEMM: C[M,N] = A[M,K] @ Bt[N,K]^T (m97-style 128^2 tile) ----------
__global__ __launch_bounds__(256) void gemm_bt(
    const unsigned short* __restrict__ A, const unsigned short* __restrict__ Bt,
    unsigned short* __restrict__ C, int M, int N, int K) {
  __shared__ __align__(16) unsigned short As[128 * 64];
  __shared__ __align__(16) unsigned short Bs[128 * 64];
  const int tid = threadIdx.x;
  const long row0 = (long)blockIdx.x * 128;
  const long col0 = (long)blockIdx.y * 128;
  const int lane = tid & 63;
  const int wid = tid >> 6;
  const int ln15 = lane & 15, hi = lane >> 4;
  const int wr = (wid >> 1) * 64, wc = (wid & 1) * 64;
  const int sr = tid >> 3;        // staging row within 32-row chunk
  const int sk = (tid & 7) * 8;   // staging k-offset (elements)
  f32x4 acc[4][4] = {};

  for (int k0 = 0; k0 < K; k0 += 64) {
#pragma unroll
    for (int c = 0; c < 4; ++c) {
      gload_lds16(A  + (row0 + c * 32 + sr) * (long)K + k0 + sk, &As[(c * 256 + tid) * 8]);
      gload_lds16(Bt + (col0 + c * 32 + sr) * (long)K + k0 + sk, &Bs[(c * 256 + tid) * 8]);
    }
    __syncthreads();
#pragma unroll
    for (int kk = 0; kk < 64; kk += 32) {
      short8 a[4], b[4];
#pragma unroll
      for (int m = 0; m < 4; ++m)
        a[m] = *(const short8*)&As[(wr + m * 16 + ln15) * 64 + kk + hi * 8];
#pragma unroll
      for (int n = 0; n < 4; ++n)
        b[n] = *(const short8*)&Bs[(wc + n * 16 + ln15) * 64 + kk + hi * 8];
#pragma unroll
      for (int m = 0; m < 4; ++m)
#pragma unroll
        for (int n = 0; n < 4; ++n)
          acc[m][n] = __builtin_amdgcn_mfma_f32_16x16x32_bf16(a[m], b[n], acc[m][n], 0, 0, 0);
    }
    __syncthreads();
  }
#pragma unroll
  for (int m = 0; m < 4; ++m)
#pragma unroll
    for (int n = 0; n < 4; ++n) {
#pragma unroll
      for (int r = 0; r < 4; ++r) {
        long row = row0 + wr + m * 16 + hi * 4 + r;
        long col = col0 + wc + n * 16 + ln15;
        C[row * N + col] = f2bf(acc[m][n][r]);
      }
    }
}

// ---------- sparse aggregation: out_i = dis_i * (sum_j dis_j * T_j + dis_i * T_i) ----------
__global__ __launch_bounds__(256) void aggregate_relu(
    const unsigned short* __restrict__ T, const int* __restrict__ cnt,
    const int* __restrict__ adj, const float* __restrict__ dis,
    const float* __restrict__ bias, unsigned short* __restrict__ H) {
  const int i = blockIdx.x;
  const int t = threadIdx.x;  // feature pair: feats 2t, 2t+1 of 512
  __shared__ int js[CAP];
  __shared__ float ws[CAP];
  int n = cnt[i]; if (n > CAP) n = CAP;
  if (t < CAP && t < n) { int j = adj[i * CAP + t]; js[t] = j; ws[t] = dis[j]; }
  __syncthreads();
  const float di = dis[i];
  unsigned int u = *(const unsigned int*)&T[(long)i * 512 + t * 2];
  float a0 = di * bflo(u), a1 = di * bfhi(u);   // extra +I self-loop term
  for (int e = 0; e < n; ++e) {
    unsigned int v = *(const unsigned int*)&T[(long)js[e] * 512 + t * 2];
    float w = ws[e];
    a0 += w * bflo(v); a1 += w * bfhi(v);
  }
  float h0 = fmaxf(di * a0 + bias[t * 2], 0.f);
  float h1 = fmaxf(di * a1 + bias[t * 2 + 1], 0.f);
  unsigned int o = (unsigned int)f2bf(h0) | ((unsigned int)f2bf(h1) << 16);
  *(unsigned int*)&H[(long)i * 512 + t * 2] = o;
}

__global__ __launch_bounds__(128) void aggregate_out(
    const unsigned short* __restrict__ T, const int* __restrict__ cnt,
    const int* __restrict__ adj, const float* __restrict__ dis,
    const float* __restrict__ bias, float* __restrict__ out) {
  const int i = blockIdx.x;
  const int t = threadIdx.x;  // feats 2t, 2t+1 of 256
  __shared__ int js[CAP];
  __shared__ float ws[CAP];
  int n = cnt[i]; if (n > CAP) n = CAP;
  if (t < n) { int j = adj[i * CAP + t]; js[t] = j; ws[t] = dis[j]; }
  __syncthreads();
  const float di = dis[i];
  unsigned int u = *(const unsigned int*)&T[(long)i * 256 + t * 2];
  float a0 = di * bflo(u), a1 = di * bfhi(u);
  for (int e = 0; e < n; ++e) {
    unsigned int v = *(const unsigned int*)&T[(long)js[e] * 256 + t * 2];
    float w = ws[e];
    a0 += w * bflo(v); a1 += w * bfhi(v);
  }
  float2 o;
  o.x = di * a0 + bias[t * 2];
  o.y = di * a1 + bias[t * 2 + 1];
  *(float2*)&out[(long)i * 256 + t * 2] = o;
}

extern "C" void kernel_launch(void* const* d_in, const int* in_sizes, int n_in,
                              void* d_out, int out_size, void* d_ws, size_t ws_size,
                              hipStream_t stream) {
  const float* x  = (const float*)d_in[0];
  const int*   ei = (const int*)d_in[1];
  const float* W1 = (const float*)d_in[2];
  const float* b1 = (const float*)d_in[3];
  const float* W2 = (const float*)d_in[4];
  const float* b2 = (const float*)d_in[5];
  float* out = (float*)d_out;

  char* ws = (char*)d_ws;
  unsigned int* bitmap = (unsigned int*)ws;  ws += 8388608;              // 8192*8192 bits
  int* cnt   = (int*)ws;                     ws += 32768;
  int* adj   = (int*)ws;                     ws += (size_t)N_NODES * CAP * 4;
  float* dis = (float*)ws;                   ws += 32768;
  unsigned short* Xb  = (unsigned short*)ws; ws += (size_t)N_NODES * IN_F * 2;
  unsigned short* W1t = (unsigned short*)ws; ws += (size_t)IN_F * HID * 2;
  unsigned short* W2t = (unsigned short*)ws; ws += (size_t)HID * OUT_F * 2;
  unsigned short* T1  = (unsigned short*)ws; ws += (size_t)N_NODES * HID * 2;
  unsigned short* H   = (unsigned short*)ws; ws += (size_t)N_NODES * HID * 2;
  unsigned short* T2  = (unsigned short*)ws; ws += (size_t)N_NODES * OUT_F * 2;

  hipMemsetAsync(bitmap, 0, 8388608 + 32768, stream);  // bitmap + cnt (contiguous)

  build_adj<<<N_EDGES / 256, 256, 0, stream>>>(ei, bitmap, cnt, adj);
  calc_dis<<<N_NODES / 256, 256, 0, stream>>>(cnt, dis);

  cvt_bf16_vec<<<(N_NODES * IN_F / 4 + 255) / 256, 256, 0, stream>>>(x, Xb, N_NODES * IN_F / 4);
  transpose_bf16<<<(IN_F * HID + 255) / 256, 256, 0, stream>>>(W1, W1t, IN_F, HID);
  transpose_bf16<<<(HID * OUT_F + 255) / 256, 256, 0, stream>>>(W2, W2t, HID, OUT_F);

  // layer 1: T1 = X @ W1 ; H = relu(Ahat * T1 + b1)
  gemm_bt<<<dim3(64, 4), 256, 0, stream>>>(Xb, W1t, T1, N_NODES, HID, IN_F);
  aggregate_relu<<<N_NODES, 256, 0, stream>>>(T1, cnt, adj, dis, b1, H);

  // layer 2: T2 = H @ W2 ; out = Ahat * T2 + b2
  gemm_bt<<<dim3(64, 2), 256, 0, stream>>>(H, W2t, T2, N_NODES, OUT_F, HID);
  aggregate_out<<<N_NODES, 128, 0, stream>>>(T2, cnt, adj, dis, b2, out);
}

// Round 2
// 175.052 us; speedup vs baseline: 1.0308x; 1.0308x over previous
//
#include <hip/hip_runtime.h>
#include <hip/hip_bf16.h>
#include <stdint.h>

#define N_NODES 8192
#define N_EDGES 262144
#define IN_F 512
#define HID 512
#define OUT_F 256
#define CAP 128   // max distinct out-neighbors; Poisson(32) => P(>128) ~ 0

typedef __attribute__((ext_vector_type(8))) short short8;
typedef __attribute__((ext_vector_type(4))) float f32x4;

// ---------- bf16 helpers (RNE) ----------
__device__ __forceinline__ float bflo(unsigned int u) {
  union { unsigned int x; float f; } c; c.x = u << 16; return c.f;
}
__device__ __forceinline__ float bfhi(unsigned int u) {
  union { unsigned int x; float f; } c; c.x = u & 0xffff0000u; return c.f;
}
__device__ __forceinline__ unsigned short f2bf(float f) {
  union { float f; unsigned int u; } c; c.f = f;
  unsigned int r = c.u + 0x7fffu + ((c.u >> 16) & 1u);
  return (unsigned short)(r >> 16);
}

__device__ __forceinline__ void gload_lds16(const void* g, void* l) {
  __builtin_amdgcn_global_load_lds((const __attribute__((address_space(1))) void*)g,
                                   (__attribute__((address_space(3))) void*)l, 16, 0, 0);
}

// ---------- graph build (dedup via bitmap; degree = distinct + self-loop) ----------
__global__ __launch_bounds__(256) void build_adj(
    const int* __restrict__ ei, unsigned int* __restrict__ bitmap,
    int* __restrict__ cnt, int* __restrict__ adj) {
  int e = blockIdx.x * blockDim.x + threadIdx.x;
  if (e >= N_EDGES) return;
  int i = ei[e];
  int j = ei[N_EDGES + e];
  int lin = i * N_NODES + j;
  unsigned int bit = 1u << (lin & 31);
  unsigned int old = atomicOr(&bitmap[lin >> 5], bit);
  if (!(old & bit)) {
    int p = atomicAdd(&cnt[i], 1);
    if (p < CAP) adj[i * CAP + p] = j;
  }
}

// ---------- dtype converts ----------
__global__ __launch_bounds__(256) void cvt_bf16_vec(
    const float* __restrict__ in, unsigned short* __restrict__ out, int n4) {
  int idx = blockIdx.x * blockDim.x + threadIdx.x;
  if (idx >= n4) return;
  const float4 v = ((const float4*)in)[idx];
  uint2 o;
  o.x = (unsigned int)f2bf(v.x) | ((unsigned int)f2bf(v.y) << 16);
  o.y = (unsigned int)f2bf(v.z) | ((unsigned int)f2bf(v.w) << 16);
  ((uint2*)out)[idx] = o;
}

// both weight transposes fused into one launch
__global__ __launch_bounds__(256) void prep_weights(
    const float* __restrict__ W1, const float* __restrict__ W2,
    unsigned short* __restrict__ W1t, unsigned short* __restrict__ W2t) {
  int idx = blockIdx.x * blockDim.x + threadIdx.x;
  if (idx < IN_F * HID) {
    int k = idx >> 9, n = idx & 511;          // W1 [512][512]
    W1t[n * IN_F + k] = f2bf(W1[idx]);
  } else {
    int r = idx - IN_F * HID;                 // W2 [512][256]
    if (r < HID * OUT_F) {
      int k = r >> 8, n = r & 255;
      W2t[n * HID + k] = f2bf(W2[r]);
    }
  }
}

// ---------- bf16 MFMA GEMM: C[M,N] = A[M,K] @ Bt[N,K]^T ----------
template<int BM, int BN>
__global__ __launch_bounds__(256) void gemm_bt(
    const unsigned short* __restrict__ A, const unsigned short* __restrict__ Bt,
    unsigned short* __restrict__ C, int M, int N, int K) {
  constexpr int MR = BM / 32, NR = BN / 32;   // frag repeats per wave; also staging chunks
  __shared__ __align__(16) unsigned short As[BM * 64];
  __shared__ __align__(16) unsigned short Bs[BN * 64];
  const int tid = threadIdx.x;
  const long row0 = (long)blockIdx.x * BM;
  const long col0 = (long)blockIdx.y * BN;
  const int lane = tid & 63;
  const int wid = tid >> 6;
  const int ln15 = lane & 15, hi = lane >> 4;
  const int wr = (wid >> 1) * (BM / 2), wc = (wid & 1) * (BN / 2);
  const int sr = tid >> 3;        // staging row within 32-row chunk
  const int sk = (tid & 7) * 8;   // staging k-offset (elements)
  f32x4 acc[MR][NR] = {};

  for (int k0 = 0; k0 < K; k0 += 64) {
#pragma unroll
    for (int c = 0; c < MR; ++c)
      gload_lds16(A  + (row0 + c * 32 + sr) * (long)K + k0 + sk, &As[(c * 256 + tid) * 8]);
#pragma unroll
    for (int c = 0; c < NR; ++c)
      gload_lds16(Bt + (col0 + c * 32 + sr) * (long)K + k0 + sk, &Bs[(c * 256 + tid) * 8]);
    __syncthreads();
#pragma unroll
    for (int kk = 0; kk < 64; kk += 32) {
      short8 a[MR], b[NR];
#pragma unroll
      for (int m = 0; m < MR; ++m)
        a[m] = *(const short8*)&As[(wr + m * 16 + ln15) * 64 + kk + hi * 8];
#pragma unroll
      for (int n = 0; n < NR; ++n)
        b[n] = *(const short8*)&Bs[(wc + n * 16 + ln15) * 64 + kk + hi * 8];
#pragma unroll
      for (int m = 0; m < MR; ++m)
#pragma unroll
        for (int n = 0; n < NR; ++n)
          acc[m][n] = __builtin_amdgcn_mfma_f32_16x16x32_bf16(a[m], b[n], acc[m][n], 0, 0, 0);
    }
    __syncthreads();
  }
#pragma unroll
  for (int m = 0; m < MR; ++m)
#pragma unroll
    for (int n = 0; n < NR; ++n)
#pragma unroll
      for (int r = 0; r < 4; ++r) {
        long row = row0 + wr + m * 16 + hi * 4 + r;
        long col = col0 + wc + n * 16 + ln15;
        C[row * N + col] = f2bf(acc[m][n][r]);
      }
}

// ---------- aggregation: out_i = di*(sum_j dj*T_j + di*T_i) [+bias, relu] ----------
// 4 waves split the neighbor list; each wave reads full 1KB row as uint4 (16B/lane).
__global__ __launch_bounds__(256) void aggregate_relu(
    const unsigned short* __restrict__ T, const int* __restrict__ cnt,
    const int* __restrict__ adj, const float* __restrict__ bias,
    unsigned short* __restrict__ H) {
  const int i = blockIdx.x;
  const int tid = threadIdx.x;
  const int lane = tid & 63, w = tid >> 6;
  __shared__ int js[CAP];
  __shared__ float ws[CAP];
  __shared__ float part[4][512];
  int n = cnt[i]; if (n > CAP) n = CAP;
  if (tid < n) { int j = adj[i * CAP + tid]; js[tid] = j; ws[tid] = rsqrtf((float)(cnt[j] + 1)); }
  __syncthreads();
  float a[8] = {};
  for (int e = w; e < n; e += 4) {
    const uint4 v = *(const uint4*)&T[(long)js[e] * 512 + lane * 8];
    float wj = ws[e];
    a[0] += wj * bflo(v.x); a[1] += wj * bfhi(v.x);
    a[2] += wj * bflo(v.y); a[3] += wj * bfhi(v.y);
    a[4] += wj * bflo(v.z); a[5] += wj * bfhi(v.z);
    a[6] += wj * bflo(v.w); a[7] += wj * bfhi(v.w);
  }
  *(float4*)&part[w][lane * 8]     = make_float4(a[0], a[1], a[2], a[3]);
  *(float4*)&part[w][lane * 8 + 4] = make_float4(a[4], a[5], a[6], a[7]);
  __syncthreads();
  const float di = rsqrtf((float)(cnt[i] + 1));
  unsigned int u = *(const unsigned int*)&T[(long)i * 512 + tid * 2];
  float s0 = part[0][2*tid]   + part[1][2*tid]   + part[2][2*tid]   + part[3][2*tid]   + di * bflo(u);
  float s1 = part[0][2*tid+1] + part[1][2*tid+1] + part[2][2*tid+1] + part[3][2*tid+1] + di * bfhi(u);
  const float2 bb = *(const float2*)&bias[2 * tid];
  float h0 = fmaxf(di * s0 + bb.x, 0.f);
  float h1 = fmaxf(di * s1 + bb.y, 0.f);
  *(unsigned int*)&H[(long)i * 512 + tid * 2] =
      (unsigned int)f2bf(h0) | ((unsigned int)f2bf(h1) << 16);
}

__global__ __launch_bounds__(256) void aggregate_out(
    const unsigned short* __restrict__ T, const int* __restrict__ cnt,
    const int* __restrict__ adj, const float* __restrict__ bias,
    float* __restrict__ out) {
  const int i = blockIdx.x;
  const int tid = threadIdx.x;
  const int lane = tid & 63, w = tid >> 6;
  __shared__ int js[CAP];
  __shared__ float ws[CAP];
  __shared__ float part[4][256];
  int n = cnt[i]; if (n > CAP) n = CAP;
  if (tid < n) { int j = adj[i * CAP + tid]; js[tid] = j; ws[tid] = rsqrtf((float)(cnt[j] + 1)); }
  __syncthreads();
  float a[4] = {};
  for (int e = w; e < n; e += 4) {
    const uint2 v = *(const uint2*)&T[(long)js[e] * 256 + lane * 4];
    float wj = ws[e];
    a[0] += wj * bflo(v.x); a[1] += wj * bfhi(v.x);
    a[2] += wj * bflo(v.y); a[3] += wj * bfhi(v.y);
  }
  *(float4*)&part[w][lane * 4] = make_float4(a[0], a[1], a[2], a[3]);
  __syncthreads();
  const float di = rsqrtf((float)(cnt[i] + 1));
  float self = di * __uint_as_float(((unsigned int)T[(long)i * 256 + tid]) << 16);
  float s = part[0][tid] + part[1][tid] + part[2][tid] + part[3][tid] + self;
  out[(long)i * 256 + tid] = di * s + bias[tid];
}

extern "C" void kernel_launch(void* const* d_in, const int* in_sizes, int n_in,
                              void* d_out, int out_size, void* d_ws, size_t ws_size,
                              hipStream_t stream) {
  const float* x  = (const float*)d_in[0];
  const int*   ei = (const int*)d_in[1];
  const float* W1 = (const float*)d_in[2];
  const float* b1 = (const float*)d_in[3];
  const float* W2 = (const float*)d_in[4];
  const float* b2 = (const float*)d_in[5];
  float* out = (float*)d_out;

  char* ws = (char*)d_ws;
  unsigned int* bitmap = (unsigned int*)ws;  ws += 8388608;              // 8192^2 bits
  int* cnt   = (int*)ws;                     ws += 32768;
  int* adj   = (int*)ws;                     ws += (size_t)N_NODES * CAP * 4;
  unsigned short* Xb  = (unsigned short*)ws; ws += (size_t)N_NODES * IN_F * 2;
  unsigned short* W1t = (unsigned short*)ws; ws += (size_t)IN_F * HID * 2;
  unsigned short* W2t = (unsigned short*)ws; ws += (size_t)HID * OUT_F * 2;
  unsigned short* T1  = (unsigned short*)ws; ws += (size_t)N_NODES * HID * 2;
  unsigned short* H   = (unsigned short*)ws; ws += (size_t)N_NODES * HID * 2;
  unsigned short* T2  = (unsigned short*)ws; ws += (size_t)N_NODES * OUT_F * 2;

  hipMemsetAsync(bitmap, 0, 8388608 + 32768, stream);  // bitmap + cnt contiguous

  build_adj<<<N_EDGES / 256, 256, 0, stream>>>(ei, bitmap, cnt, adj);

  cvt_bf16_vec<<<N_NODES * IN_F / 4 / 256, 256, 0, stream>>>(x, Xb, N_NODES * IN_F / 4);
  prep_weights<<<(IN_F * HID + HID * OUT_F) / 256, 256, 0, stream>>>(W1, W2, W1t, W2t);

  // layer 1: T1 = X @ W1 ; H = relu(Ahat * T1 + b1)
  gemm_bt<128, 64><<<dim3(N_NODES / 128, HID / 64), 256, 0, stream>>>(Xb, W1t, T1, N_NODES, HID, IN_F);
  aggregate_relu<<<N_NODES, 256, 0, stream>>>(T1, cnt, adj, b1, H);

  // layer 2: T2 = H @ W2 ; out = Ahat * T2 + b2
  gemm_bt<64, 64><<<dim3(N_NODES / 64, OUT_F / 64), 256, 0, stream>>>(H, W2t, T2, N_NODES, OUT_F, HID);
  aggregate_out<<<N_NODES, 256, 0, stream>>>(T2, cnt, adj, b2, out);
}